// Round 10
// baseline (43.787 us; speedup 1.0000x reference)
//
#include <hip/hip_runtime.h>

// Fixed-shape problem
#define NBATCH 4
#define NPTS   8192
#define MTGT   8192
#define BN     (NBATCH*NPTS)      // 32768 sources
#define TPB    256
#define SPT    8                  // sources per thread (R2-proven f32x2 loop)
#define SPB    (TPB*SPT)          // 2048 sources per block (slice)
#define NXBLK  (BN/SPB)           // 16 slices (4 per batch)
#define CHUNK  128                // targets staged per block
#define NCHUNK (MTGT/CHUNK)       // 64 -> grid 16x64 = 1024 blocks (4/CU)

typedef float f32x2 __attribute__((ext_vector_type(2)));

__device__ __forceinline__ f32x2 pkfma(f32x2 a, f32x2 b, f32x2 c) {
    return __builtin_elementwise_fma(a, b, c);
}
__device__ __forceinline__ f32x2 pkmin(f32x2 a, f32x2 b) {
    return __builtin_elementwise_min(a, b);
}

// wspart layout: [slice][chunk][source-in-slice]; writer and reader coalesced;
// plain streaming stores, no atomics anywhere -> bit-deterministic.

// Per source point, min over one 128-target chunk of d' = ||t||^2 - 2 s.t
// (exact sq distance = d' + ||s||^2, added in reduce)
__global__ __launch_bounds__(TPB, 4) void nn_min_kernel(const float* __restrict__ src,
                                                        const float* __restrict__ tgt,
                                                        float* __restrict__ wspart) {
    __shared__ float  raw[CHUNK * 3];   // 1.5 KiB
    __shared__ float4 lt[CHUNK];        // 2 KiB: (x,y,z,||t||^2); invalid -> 1e30

    const int tid = threadIdx.x;
    const int bx  = blockIdx.x;          // 0..15 (source slice)
    const int c   = blockIdx.y;          // 0..63 (target chunk)
    const int b   = bx >> 2;             // 4 slices per batch

    // ---- stage CHUNK targets (1.5 KiB, coalesced float4) ----
    const float4* tv = reinterpret_cast<const float4*>(
        tgt + ((size_t)b * MTGT + (size_t)c * CHUNK) * 3);
    if (tid < CHUNK * 3 / 4) reinterpret_cast<float4*>(raw)[tid] = tv[tid];
    __syncthreads();
    if (tid < CHUNK) {
        float x = raw[3 * tid], y = raw[3 * tid + 1], z = raw[3 * tid + 2];
        float tsq = fmaf(x, x, fmaf(y, y, z * z));
        bool valid = (x != 0.f) || (y != 0.f) || (z != 0.f);
        lt[tid] = make_float4(x, y, z, valid ? tsq : 1e30f);
    }
    __syncthreads();

    // ---- 8 source points: 6 contiguous float4 = 96 B per thread ----
    const int s0 = bx * SPB + tid * SPT;
    const float4* sv = reinterpret_cast<const float4*>(src + (size_t)s0 * 3);
    float4 q0 = sv[0], q1 = sv[1], q2 = sv[2], q3 = sv[3], q4 = sv[4], q5 = sv[5];
    float sxs[8] = {q0.x, q0.w, q1.z, q2.y, q3.x, q3.w, q4.z, q5.y};
    float sys[8] = {q0.y, q1.x, q1.w, q2.z, q3.y, q4.x, q4.w, q5.z};
    float szs[8] = {q0.z, q1.y, q2.x, q2.w, q3.z, q4.y, q5.x, q5.w};

    f32x2 ax[4], ay[4], az[4], bmE[4], bmO[4];
#pragma unroll
    for (int p = 0; p < 4; ++p) {
        ax[p] = f32x2{-2.f * sxs[2 * p], -2.f * sxs[2 * p + 1]};
        ay[p] = f32x2{-2.f * sys[2 * p], -2.f * sys[2 * p + 1]};
        az[p] = f32x2{-2.f * szs[2 * p], -2.f * szs[2 * p + 1]};
        bmE[p] = f32x2{3e38f, 3e38f};
        bmO[p] = f32x2{3e38f, 3e38f};
    }

    // ---- R2-proven inner loop: 1 broadcast ds_read_b128 feeds 8 sources;
    //      even/odd accumulators break the min dependency chain ----
#pragma unroll 2
    for (int m = 0; m < CHUNK; m += 2) {
        float4 t0 = lt[m], t1 = lt[m + 1];
        f32x2 t0x = {t0.x, t0.x}, t0y = {t0.y, t0.y}, t0z = {t0.z, t0.z}, t0w = {t0.w, t0.w};
        f32x2 t1x = {t1.x, t1.x}, t1y = {t1.y, t1.y}, t1z = {t1.z, t1.z}, t1w = {t1.w, t1.w};
#pragma unroll
        for (int p = 0; p < 4; ++p) {
            bmE[p] = pkmin(bmE[p], pkfma(ax[p], t0x, pkfma(ay[p], t0y, pkfma(az[p], t0z, t0w))));
            bmO[p] = pkmin(bmO[p], pkfma(ax[p], t1x, pkfma(ay[p], t1y, pkfma(az[p], t1z, t1w))));
        }
    }

    f32x2 r0 = pkmin(bmE[0], bmO[0]);
    f32x2 r1 = pkmin(bmE[1], bmO[1]);
    f32x2 r2 = pkmin(bmE[2], bmO[2]);
    f32x2 r3 = pkmin(bmE[3], bmO[3]);

    // ---- two coalesced 16B streaming stores per thread ----
    float4* wp = reinterpret_cast<float4*>(
        wspart + ((size_t)bx * NCHUNK + c) * SPB) + tid * 2;
    wp[0] = make_float4(r0.x, r0.y, r1.x, r1.y);
    wp[1] = make_float4(r2.x, r2.y, r3.x, r3.y);
}

// 128 blocks: (slice, k-of-8). Min over 64 chunk-partials (coalesced: for
// fixed (k,c) a wave reads 1 KB consecutive), then deterministic partials.
__global__ __launch_bounds__(256) void reduce_kernel(const float* __restrict__ src,
                                                     const float* __restrict__ wspart,
                                                     double* __restrict__ partials) {
    const int blk   = blockIdx.x;        // 0..127
    const int slice = blk >> 3, k = blk & 7;
    const int tid   = threadIdx.x;
    const float* wp = wspart + (size_t)slice * NCHUNK * SPB;

    const int s   = k * 256 + tid;       // source within slice
    const int gid = slice * SPB + s;

    float m = 3e38f;
#pragma unroll 4
    for (int c = 0; c < NCHUNK; ++c) m = fminf(m, wp[(size_t)c * SPB + s]);

    float sx = src[(size_t)gid * 3 + 0];
    float sy = src[(size_t)gid * 3 + 1];
    float sz = src[(size_t)gid * 3 + 2];
    bool valid = (sx != 0.f) || (sy != 0.f) || (sz != 0.f);
    float ssq = fmaf(sx, sx, fmaf(sy, sy, sz * sz));
    float sq = fmaxf(0.f, ssq + m);

    __shared__ double sh[512];
    sh[tid] = valid ? (double)sq : 0.0;
    sh[256 + tid] = valid ? 1.0 : 0.0;
    __syncthreads();
    for (int t = 128; t > 0; t >>= 1) {
        if (tid < t) { sh[tid] += sh[tid + t]; sh[256 + tid] += sh[256 + tid + t]; }
        __syncthreads();
    }
    if (tid == 0) { partials[2 * blk] = sh[0]; partials[2 * blk + 1] = sh[256]; }
}

// Fixed-order final combine: bit-deterministic scalar output.
// Batch t owns slices 4t..4t+3 -> partial blocks 32t..32t+31.
__global__ void final_kernel(const double* __restrict__ partials, float* __restrict__ out) {
    __shared__ double bmv[4];
    int t = threadIdx.x;
    if (t < 4) {
        double s = 0.0, c = 0.0;
        for (int i = 0; i < 32; ++i) {
            s += partials[2 * (t * 32 + i)];
            c += partials[2 * (t * 32 + i) + 1];
        }
        if (c < 1.0) c = 1.0;
        bmv[t] = s / (3.0 * c);
    }
    __syncthreads();
    if (t == 0) out[0] = (float)((bmv[0] + bmv[1] + bmv[2] + bmv[3]) * 0.25);
}

extern "C" void kernel_launch(void* const* d_in, const int* in_sizes, int n_in,
                              void* d_out, int out_size, void* d_ws, size_t ws_size,
                              hipStream_t stream) {
    const float* src = (const float*)d_in[0];
    const float* tgt = (const float*)d_in[1];
    float* out = (float*)d_out;

    float*  wspart   = (float*)d_ws;                                  // 8 MiB
    double* partials = (double*)((char*)d_ws +
                                 (size_t)NXBLK * NCHUNK * SPB * sizeof(float)); // 2 KiB

    nn_min_kernel<<<dim3(NXBLK, NCHUNK), dim3(TPB), 0, stream>>>(src, tgt, wspart);
    reduce_kernel<<<dim3(NXBLK * 8), dim3(256), 0, stream>>>(src, wspart, partials);
    final_kernel<<<dim3(1), dim3(64), 0, stream>>>(partials, out);
}